// Round 1
// baseline (5657.790 us; speedup 1.0000x reference)
//
#include <hip/hip_runtime.h>
#include <hip/hip_bf16.h>
#include <stdint.h>

// KNN classifier pipeline:
//   sim = features_rank @ train_features^T   [2048 x 100000] fp32
//   top-200 per row (sorted desc), softmax(sim/T), class histograms at k=10,20,100,200
//
// Phase 1: fp32 LDS-tiled GEMM into d_ws (row-chunked if ws too small).
// Phase 2: per-row radix-select (12-bit monotonic key histogram) -> compact
//          candidates -> bitonic sort -> softmax -> 4 histogram snapshots.

#define B_Q     2048
#define DIM     1024
#define NTRAIN  100000
#define MAXK    200
#define NCLS    1000
#define BM      128
#define BN      128
#define BK      16
#define HBINS   4096
#define CAP     2048
#define INV_T   (1.0f/0.07f)

// ---------------------------------------------------------------- GEMM ------
// C[crow..][col] = A[row0+crow..] . B[col]  (both row-major, dot over DIM)
// block: 128x128 C-tile, 256 threads, 8x8 micro-tile per thread.
// LDS layout transposed (As[k][row]) so compute reads are float4:
//   a-reads broadcast (free), b-reads 2-way bank aliasing (free, m136).
__global__ __launch_bounds__(256, 3)
void gemm_f32(const float* __restrict__ A, const float* __restrict__ B,
              float* __restrict__ C, int row0) {
  __shared__ float As[BK][BM];
  __shared__ float Bs[BK][BN];
  const int tid  = threadIdx.x;
  const int crow = blockIdx.x * BM;      // chunk-local row base
  const int arow = row0 + crow;          // global query row base
  const int bcol = blockIdx.y * BN;
  const int tx = tid & 15, ty = tid >> 4;

  float acc[8][8];
#pragma unroll
  for (int i = 0; i < 8; i++)
#pragma unroll
    for (int j = 0; j < 8; j++) acc[i][j] = 0.f;

  for (int kt = 0; kt < DIM; kt += BK) {
    // stage A-tile and B-tile: 512 float4 each half, 2 per thread
#pragma unroll
    for (int l = 0; l < 2; l++) {
      int id = tid * 2 + l;
      int r  = id >> 2;           // 0..127
      int k4 = (id & 3) * 4;      // 0,4,8,12
      float4 va = *(const float4*)(A + (size_t)(arow + r) * DIM + kt + k4);
      As[k4+0][r] = va.x; As[k4+1][r] = va.y; As[k4+2][r] = va.z; As[k4+3][r] = va.w;
      int bc = bcol + r; if (bc >= NTRAIN) bc = NTRAIN - 1;  // clamp; stores guarded
      float4 vb = *(const float4*)(B + (size_t)bc * DIM + kt + k4);
      Bs[k4+0][r] = vb.x; Bs[k4+1][r] = vb.y; Bs[k4+2][r] = vb.z; Bs[k4+3][r] = vb.w;
    }
    __syncthreads();
#pragma unroll
    for (int kk = 0; kk < BK; kk++) {
      float a[8], b[8];
      *(float4*)&a[0] = *(const float4*)&As[kk][ty * 4];
      *(float4*)&a[4] = *(const float4*)&As[kk][64 + ty * 4];
      *(float4*)&b[0] = *(const float4*)&Bs[kk][tx * 4];
      *(float4*)&b[4] = *(const float4*)&Bs[kk][64 + tx * 4];
#pragma unroll
      for (int i = 0; i < 8; i++)
#pragma unroll
        for (int j = 0; j < 8; j++)
          acc[i][j] = fmaf(a[i], b[j], acc[i][j]);
    }
    __syncthreads();
  }

#pragma unroll
  for (int i = 0; i < 8; i++) {
    int r = crow + ((i < 4) ? (ty * 4 + i) : (64 + ty * 4 + (i - 4)));
    float* crowp = C + (size_t)r * NTRAIN;
#pragma unroll
    for (int g = 0; g < 2; g++) {
      int c = bcol + (g ? (64 + tx * 4) : (tx * 4));
      float4 v = make_float4(acc[i][g*4+0], acc[i][g*4+1], acc[i][g*4+2], acc[i][g*4+3]);
      if (c + 3 < NTRAIN) {
        *(float4*)(crowp + c) = v;
      } else {
        float vv[4] = {v.x, v.y, v.z, v.w};
        for (int j = 0; j < 4; j++) if (c + j < NTRAIN) crowp[c + j] = vv[j];
      }
    }
  }
}

// ---------------------------------------------------- top-k + softmax -------
// one block per query row.
__global__ __launch_bounds__(256)
void topk_hist(const float* __restrict__ sim, const int* __restrict__ labels,
               float* __restrict__ out, int row0) {
  __shared__ unsigned int hist[HBINS];          // 16 KB
  __shared__ unsigned long long cand[CAP];      // 16 KB
  __shared__ unsigned int csum[256];
  __shared__ float ch[NCLS];                    // 4 KB
  __shared__ unsigned int s_cnt, s_thr;
  __shared__ float s_wsum;

  const int tid = threadIdx.x;
  const float* srow = sim + (size_t)blockIdx.x * NTRAIN;
  const int grow = row0 + blockIdx.x;

  for (int i = tid; i < HBINS; i += 256) hist[i] = 0;
  if (tid == 0) { s_cnt = 0; s_wsum = 0.f; }
  __syncthreads();

  // pass 1: 12-bit monotonic-key histogram
  for (int i = tid; i < NTRAIN; i += 256) {
    unsigned u = __float_as_uint(srow[i]);
    u ^= (unsigned)((int)u >> 31) | 0x80000000u;   // monotonic key
    atomicAdd(&hist[u >> 20], 1u);
  }
  __syncthreads();

  // find threshold bin: smallest bin t with count(key-bin >= t) >= MAXK
  unsigned s = 0;
  const int base = tid * (HBINS / 256);
#pragma unroll
  for (int b = 0; b < HBINS / 256; b++) s += hist[base + b];
  csum[tid] = s;
  __syncthreads();
  unsigned suf = 0;
  for (int j = tid + 1; j < 256; j++) suf += csum[j];
  if (suf < MAXK && suf + s >= MAXK) {            // unique owning chunk
    unsigned run = suf;
    int t = base;
    for (int b = HBINS / 256 - 1; b >= 0; b--) {
      unsigned h = hist[base + b];
      if (run + h >= MAXK) { t = base + b; break; }
      run += h;
    }
    s_thr = (unsigned)t;
  }
  __syncthreads();
  const unsigned thr = s_thr;

  // pass 2: compact candidates (key-bin >= thr); expected ~300, cap 2048
  for (int i = tid; i < NTRAIN; i += 256) {
    unsigned u = __float_as_uint(srow[i]);
    u ^= (unsigned)((int)u >> 31) | 0x80000000u;
    if ((u >> 20) >= thr) {
      unsigned p = atomicAdd(&s_cnt, 1u);
      if (p < CAP) cand[p] = ((unsigned long long)u << 32) | (unsigned)(~i);
    }
  }
  __syncthreads();
  int M = (int)s_cnt; if (M > CAP) M = CAP;
  int P = 256; while (P < M) P <<= 1;
  for (int i = M + tid; i < P; i += 256) cand[i] = 0ull;  // pad = smallest key
  __syncthreads();

  // bitonic sort desc on (value-key, ~index) -> value desc, index asc
  for (int k2 = 2; k2 <= P; k2 <<= 1) {
    for (int j = k2 >> 1; j > 0; j >>= 1) {
      for (int i = tid; i < P; i += 256) {
        int l = i ^ j;
        if (l > i) {
          unsigned long long x = cand[i], y = cand[l];
          bool desc = ((i & k2) == 0);
          if (desc ? (x < y) : (x > y)) { cand[i] = y; cand[l] = x; }
        }
      }
      __syncthreads();
    }
  }

  // softmax over top-200 + incremental class histogram snapshots
  unsigned up0 = (unsigned)(cand[0] >> 32);
  unsigned u0 = up0 ^ ((unsigned)((int)(~up0) >> 31) | 0x80000000u);
  float v0 = __uint_as_float(u0);

  float wi = 0.f; int lab = 0;
  if (tid < MAXK) {
    unsigned long long c = cand[tid];
    unsigned up = (unsigned)(c >> 32);
    unsigned u = up ^ ((unsigned)((int)(~up) >> 31) | 0x80000000u);
    float v = __uint_as_float(u);
    int idx = (int)(~(unsigned)(c & 0xFFFFFFFFull));
    lab = labels[idx];
    wi = expf((v - v0) * INV_T);
    atomicAdd(&s_wsum, wi);
  }
  for (int i = tid; i < NCLS; i += 256) ch[i] = 0.f;
  __syncthreads();
  float wn = (tid < MAXK) ? (wi / s_wsum) : 0.f;

  const int kb[5] = {0, 10, 20, 100, 200};
#pragma unroll
  for (int ph = 0; ph < 4; ph++) {
    if (tid >= kb[ph] && tid < kb[ph + 1]) atomicAdd(&ch[lab], wn);
    __syncthreads();
    float* dst = out + ((size_t)ph * B_Q + grow) * NCLS;
    for (int i = tid; i < NCLS; i += 256) dst[i] = ch[i];
    __syncthreads();
  }
}

// ---------------------------------------------------------------- launch ----
extern "C" void kernel_launch(void* const* d_in, const int* in_sizes, int n_in,
                              void* d_out, int out_size, void* d_ws, size_t ws_size,
                              hipStream_t stream) {
  const float* A      = (const float*)d_in[0];   // [2048][1024]
  const float* B      = (const float*)d_in[1];   // [100000][1024]
  const int*   labels = (const int*)d_in[2];     // [100000]
  float* out = (float*)d_out;                    // [4][2048][1000]
  float* sim = (float*)d_ws;

  // row-chunk so the sim buffer fits in ws
  size_t rows_fit = ws_size / ((size_t)NTRAIN * sizeof(float));
  int chunk = (int)((rows_fit / BM) * BM);
  if (chunk > B_Q) chunk = B_Q;
  if (chunk < BM) chunk = BM;   // minimum workable chunk (needs ~51 MB ws)

  for (int row0 = 0; row0 < B_Q; row0 += chunk) {
    int nr = (B_Q - row0 < chunk) ? (B_Q - row0) : chunk;   // multiple of BM
    dim3 gg(nr / BM, (NTRAIN + BN - 1) / BN);
    gemm_f32<<<gg, dim3(256), 0, stream>>>(A, B, sim, row0);
    topk_hist<<<dim3(nr), dim3(256), 0, stream>>>(sim, labels, out, row0);
  }
}

// Round 2
// 2586.199 us; speedup vs baseline: 2.1877x; 2.1877x over previous
//
#include <hip/hip_runtime.h>
#include <hip/hip_bf16.h>
#include <stdint.h>

// KNN classifier pipeline (round 2):
//   sim = features_rank @ train_features^T   [2048 x 100000] fp32-accurate
//   via split-bf16 MFMA:  a = a_hi + a_lo (bf16),
//   sim ~= Ahi.Bhi + Ahi.Blo + Alo.Bhi  == one bf16 GEMM with K'=3072
//   then per-row radix-select top-200 -> softmax(T=0.07) -> 4 histograms.

#define B_Q     2048
#define DIM     1024
#define NTRAIN  100000
#define MAXK    200
#define NCLS    1000
#define HBINS   4096
#define CAP     2048
#define INV_T   (1.0f/0.07f)
#define KPRIME  3072

typedef __bf16 bf16x8 __attribute__((ext_vector_type(8)));
typedef __bf16 bf16x4 __attribute__((ext_vector_type(4)));
typedef float  f32x4  __attribute__((ext_vector_type(4)));

// --------------------------------------------------------------- split ------
// Y[row][0..1023] = bf16(x) ; Y[row][1024..2047] = bf16(x - hi). pitch 2048.
__global__ __launch_bounds__(256)
void split_hi_lo(const float* __restrict__ X, __bf16* __restrict__ Y) {
  const int row = blockIdx.x;
  const int c = threadIdx.x * 4;
  float4 v = *(const float4*)(X + (size_t)row * DIM + c);
  float f[4] = {v.x, v.y, v.z, v.w};
  bf16x4 h, l;
#pragma unroll
  for (int j = 0; j < 4; j++) {
    __bf16 hi = (__bf16)f[j];
    h[j] = hi;
    l[j] = (__bf16)(f[j] - (float)hi);
  }
  *(bf16x4*)(Y + (size_t)row * 2048 + c) = h;
  *(bf16x4*)(Y + (size_t)row * 2048 + 1024 + c) = l;
}

// ---------------------------------------------------------------- GEMM ------
__device__ __forceinline__ void lds_dma16(void* g, void* l) {
  __builtin_amdgcn_global_load_lds((__attribute__((address_space(1))) void*)g,
                                   (__attribute__((address_space(3))) void*)l,
                                   16, 0, 0);
}

// 128x128 C-tile, 256 threads (4 waves 2x2), 4x4 frags of 16x16x32 bf16.
// K' = 3072: term t = k'/1024 selects (hi,hi) / (hi,lo) / (lo,hi) columns.
// LDS: linear layout forced by global_load_lds; XOR chunk swizzle applied on
// the global-read side: slot (row, kq) holds global chunk (kq ^ (row&7)).
__global__ __launch_bounds__(256, 2)
void gemm_mfma(const __bf16* __restrict__ Acat, const __bf16* __restrict__ Bcat,
               float* __restrict__ C, int row0) {
  __shared__ __bf16 sA[128 * 64];   // 16 KB
  __shared__ __bf16 sB[128 * 64];   // 16 KB

  const int tid  = threadIdx.x;
  const int lane = tid & 63;
  const int wave = tid >> 6;
  const int wm = wave & 1, wn = wave >> 1;
  const int m16 = lane & 15, quad = lane >> 4;

  const int rowL = blockIdx.x * 128;       // chunk-local row base
  const int arow = row0 + rowL;            // global query row base
  const int bcol = blockIdx.y * 128;

  f32x4 acc[4][4];
#pragma unroll
  for (int i = 0; i < 4; i++)
#pragma unroll
    for (int j = 0; j < 4; j++) acc[i][j] = (f32x4){0.f, 0.f, 0.f, 0.f};

  // staging slot (per issue): s = is*256 + tid; row = s>>3, kq = s&7
  const int s_kq[4] = {tid & 7, tid & 7, tid & 7, tid & 7};
  (void)s_kq;

  for (int kt = 0; kt < KPRIME; kt += 64) {
    const int t = kt >> 10;            // term 0,1,2
    const int k = kt & 1023;
    const int kA = (t == 2 ? 1024 : 0) + k;   // bf16 col offset in Acat
    const int kB = (t == 1 ? 1024 : 0) + k;

#pragma unroll
    for (int is = 0; is < 4; is++) {
      const int s  = is * 256 + tid;
      const int r  = s >> 3;
      const int kq = s & 7;
      const int csw = kq ^ (r & 7);                 // swizzled chunk
      const int ldsOff = __builtin_amdgcn_readfirstlane((is * 256 + wave * 64) * 16);
      // A
      void* gA = (void*)(Acat + (size_t)(arow + r) * 2048 + kA + csw * 8);
      lds_dma16(gA, (char*)sA + ldsOff);
      // B (clamp train index for the last column block)
      int n = bcol + r; if (n >= NTRAIN) n = NTRAIN - 1;
      void* gB = (void*)(Bcat + (size_t)n * 2048 + kB + csw * 8);
      lds_dma16(gB, (char*)sB + ldsOff);
    }
    asm volatile("s_waitcnt vmcnt(0)" ::: "memory");
    __syncthreads();

#pragma unroll
    for (int ks = 0; ks < 2; ks++) {
      bf16x8 aF[4], bF[4];
      const int c = ks * 4 + quad;
#pragma unroll
      for (int i = 0; i < 4; i++) {
        const int m = wm * 64 + i * 16 + m16;
        aF[i] = *(const bf16x8*)(sA + (size_t)(m * 8 + (c ^ (m & 7))) * 8);
        const int n = wn * 64 + i * 16 + m16;
        bF[i] = *(const bf16x8*)(sB + (size_t)(n * 8 + (c ^ (n & 7))) * 8);
      }
#pragma unroll
      for (int i = 0; i < 4; i++)
#pragma unroll
        for (int j = 0; j < 4; j++)
          acc[i][j] = __builtin_amdgcn_mfma_f32_16x16x32_bf16(aF[i], bF[j], acc[i][j], 0, 0, 0);
    }
    __syncthreads();
  }

  // epilogue: D col = lane&15 (n), row = quad*4 + reg (m)
#pragma unroll
  for (int i = 0; i < 4; i++) {
    const int mr = rowL + wm * 64 + i * 16 + quad * 4;
#pragma unroll
    for (int j = 0; j < 4; j++) {
      const int col = bcol + wn * 64 + j * 16 + m16;
      if (col < NTRAIN) {
#pragma unroll
        for (int r = 0; r < 4; r++)
          C[(size_t)(mr + r) * NTRAIN + col] = acc[i][j][r];
      }
    }
  }
}

// ---------------------------------------------------- top-k + softmax -------
__global__ __launch_bounds__(256)
void topk_hist(const float* __restrict__ sim, const int* __restrict__ labels,
               float* __restrict__ out, int row0) {
  __shared__ unsigned int hist[HBINS];
  __shared__ unsigned long long cand[CAP];
  __shared__ unsigned int csum[256];
  __shared__ float ch[NCLS];
  __shared__ unsigned int s_cnt, s_thr;
  __shared__ float s_wsum;

  const int tid = threadIdx.x;
  const float* srow = sim + (size_t)blockIdx.x * NTRAIN;
  const int grow = row0 + blockIdx.x;

  for (int i = tid; i < HBINS; i += 256) hist[i] = 0;
  if (tid == 0) { s_cnt = 0; s_wsum = 0.f; }
  __syncthreads();

  for (int i = tid; i < NTRAIN; i += 256) {
    unsigned u = __float_as_uint(srow[i]);
    u ^= (unsigned)((int)u >> 31) | 0x80000000u;
    atomicAdd(&hist[u >> 20], 1u);
  }
  __syncthreads();

  unsigned s = 0;
  const int base = tid * (HBINS / 256);
#pragma unroll
  for (int b = 0; b < HBINS / 256; b++) s += hist[base + b];
  csum[tid] = s;
  __syncthreads();
  unsigned suf = 0;
  for (int j = tid + 1; j < 256; j++) suf += csum[j];
  if (suf < MAXK && suf + s >= MAXK) {
    unsigned run = suf;
    int t = base;
    for (int b = HBINS / 256 - 1; b >= 0; b--) {
      unsigned h = hist[base + b];
      if (run + h >= MAXK) { t = base + b; break; }
      run += h;
    }
    s_thr = (unsigned)t;
  }
  __syncthreads();
  const unsigned thr = s_thr;

  for (int i = tid; i < NTRAIN; i += 256) {
    unsigned u = __float_as_uint(srow[i]);
    u ^= (unsigned)((int)u >> 31) | 0x80000000u;
    if ((u >> 20) >= thr) {
      unsigned p = atomicAdd(&s_cnt, 1u);
      if (p < CAP) cand[p] = ((unsigned long long)u << 32) | (unsigned)(~i);
    }
  }
  __syncthreads();
  int M = (int)s_cnt; if (M > CAP) M = CAP;
  int P = 256; while (P < M) P <<= 1;
  for (int i = M + tid; i < P; i += 256) cand[i] = 0ull;
  __syncthreads();

  for (int k2 = 2; k2 <= P; k2 <<= 1) {
    for (int j = k2 >> 1; j > 0; j >>= 1) {
      for (int i = tid; i < P; i += 256) {
        int l = i ^ j;
        if (l > i) {
          unsigned long long x = cand[i], y = cand[l];
          bool desc = ((i & k2) == 0);
          if (desc ? (x < y) : (x > y)) { cand[i] = y; cand[l] = x; }
        }
      }
      __syncthreads();
    }
  }

  unsigned up0 = (unsigned)(cand[0] >> 32);
  unsigned u0 = up0 ^ ((unsigned)((int)(~up0) >> 31) | 0x80000000u);
  float v0 = __uint_as_float(u0);

  float wi = 0.f; int lab = 0;
  if (tid < MAXK) {
    unsigned long long c = cand[tid];
    unsigned up = (unsigned)(c >> 32);
    unsigned u = up ^ ((unsigned)((int)(~up) >> 31) | 0x80000000u);
    float v = __uint_as_float(u);
    int idx = (int)(~(unsigned)(c & 0xFFFFFFFFull));
    lab = labels[idx];
    wi = expf((v - v0) * INV_T);
    atomicAdd(&s_wsum, wi);
  }
  for (int i = tid; i < NCLS; i += 256) ch[i] = 0.f;
  __syncthreads();
  float wn = (tid < MAXK) ? (wi / s_wsum) : 0.f;

  const int kb[5] = {0, 10, 20, 100, 200};
#pragma unroll
  for (int ph = 0; ph < 4; ph++) {
    if (tid >= kb[ph] && tid < kb[ph + 1]) atomicAdd(&ch[lab], wn);
    __syncthreads();
    float* dst = out + ((size_t)ph * B_Q + grow) * NCLS;
    for (int i = tid; i < NCLS; i += 256) dst[i] = ch[i];
    __syncthreads();
  }
}

// ---------------------------------------------------------------- launch ----
extern "C" void kernel_launch(void* const* d_in, const int* in_sizes, int n_in,
                              void* d_out, int out_size, void* d_ws, size_t ws_size,
                              hipStream_t stream) {
  const float* A      = (const float*)d_in[0];
  const float* B      = (const float*)d_in[1];
  const int*   labels = (const int*)d_in[2];
  float* out = (float*)d_out;

  char* ws = (char*)d_ws;
  const size_t acat_bytes = (size_t)B_Q * 2048 * 2;        // 8.39 MB
  const size_t bcat_bytes = (size_t)NTRAIN * 2048 * 2;     // 409.6 MB
  __bf16* Acat = (__bf16*)ws;
  __bf16* Bcat = (__bf16*)(ws + acat_bytes);
  float*  sim  = (float*)(ws + acat_bytes + bcat_bytes);

  size_t sim_bytes = (ws_size > acat_bytes + bcat_bytes)
                       ? ws_size - acat_bytes - bcat_bytes : 0;
  long rows_fit = (long)(sim_bytes / ((size_t)NTRAIN * sizeof(float)));
  int chunk = (int)((rows_fit / 128) * 128);
  if (chunk > B_Q) chunk = B_Q;
  if (chunk < 128) chunk = 128;   // ws proven >= 819 MB in round 1

  split_hi_lo<<<dim3(B_Q),    dim3(256), 0, stream>>>(A, Acat);
  split_hi_lo<<<dim3(NTRAIN), dim3(256), 0, stream>>>(B, Bcat);

  for (int row0 = 0; row0 < B_Q; row0 += chunk) {
    int nr = (B_Q - row0 < chunk) ? (B_Q - row0) : chunk;
    dim3 gg(nr / 128, (NTRAIN + 127) / 128);
    gemm_mfma<<<gg, dim3(256), 0, stream>>>(Acat, Bcat, sim, row0);
    topk_hist<<<dim3(nr), dim3(256), 0, stream>>>(sim, labels, out, row0);
  }
}

// Round 4
// 2244.255 us; speedup vs baseline: 2.5210x; 1.1524x over previous
//
#include <hip/hip_runtime.h>
#include <hip/hip_bf16.h>
#include <stdint.h>

// KNN classifier pipeline (round 4 = round 3 + tail-coverage bugfix):
//   sim = features_rank @ train_features^T  via split-bf16 MFMA (K'=3072)
//   topk: single-read sample-threshold stash select -> sort -> softmax -> hists
//
// Round-3 post-mortem: streaming pass missed indices 99584..99999 (tail was a
// single strided read, not a loop) -> absmax 1.0. Fixed: strided tail loop.

#define B_Q     2048
#define DIM     1024
#define NTRAIN  100000
#define MAXK    200
#define NCLS    1000
#define INV_T   (1.0f/0.07f)
#define KPRIME  3072

#define HB      2048      // linear hist bins
#define STCAP   4864      // LDS stash capacity (values >= t0)
#define C2CAP   1024      // filtered-candidate capacity
#define SLOWCAP 4096      // fallback compact capacity

typedef __bf16 bf16x8 __attribute__((ext_vector_type(8)));
typedef float  f32x4  __attribute__((ext_vector_type(4)));

// --------------------------------------------------------------- split ------
// grid-stride, 8 floats / iter: deep memory-level parallelism (latency fix).
__global__ __launch_bounds__(256)
void split_hi_lo(const float* __restrict__ X, __bf16* __restrict__ Y, int rows) {
  const int nth = gridDim.x * 256;
  const int total = rows * (DIM / 8);
  for (int g = blockIdx.x * 256 + threadIdx.x; g < total; g += nth) {
    const int row = g >> 7, c8 = (g & 127) * 8;
    const float* p = X + (size_t)row * DIM + c8;
    float4 a = ((const float4*)p)[0], b = ((const float4*)p)[1];
    float f[8] = {a.x, a.y, a.z, a.w, b.x, b.y, b.z, b.w};
    bf16x8 h, l;
#pragma unroll
    for (int j = 0; j < 8; j++) {
      __bf16 hi = (__bf16)f[j];
      h[j] = hi;
      l[j] = (__bf16)(f[j] - (float)hi);
    }
    *(bf16x8*)(Y + (size_t)row * 2048 + c8) = h;
    *(bf16x8*)(Y + (size_t)row * 2048 + 1024 + c8) = l;
  }
}

// ---------------------------------------------------------------- GEMM ------
__device__ __forceinline__ void lds_dma16(void* g, void* l) {
  __builtin_amdgcn_global_load_lds((__attribute__((address_space(1))) void*)g,
                                   (__attribute__((address_space(3))) void*)l,
                                   16, 0, 0);
}

// 128x128 C-tile, 256 threads (4 waves 2x2), 4x4 frags of 16x16x32 bf16.
// K'=3072: term t=k'/1024 selects (hi,hi)/(hi,lo)/(lo,hi). XOR chunk swizzle.
__global__ __launch_bounds__(256, 2)
void gemm_mfma(const __bf16* __restrict__ Acat, const __bf16* __restrict__ Bcat,
               float* __restrict__ C, int row0) {
  __shared__ __bf16 sA[128 * 64];
  __shared__ __bf16 sB[128 * 64];

  const int tid  = threadIdx.x;
  const int lane = tid & 63;
  const int wave = tid >> 6;
  const int wm = wave & 1, wn = wave >> 1;
  const int m16 = lane & 15, quad = lane >> 4;

  const int rowL = blockIdx.x * 128;
  const int arow = row0 + rowL;
  const int bcol = blockIdx.y * 128;

  f32x4 acc[4][4];
#pragma unroll
  for (int i = 0; i < 4; i++)
#pragma unroll
    for (int j = 0; j < 4; j++) acc[i][j] = (f32x4){0.f, 0.f, 0.f, 0.f};

  for (int kt = 0; kt < KPRIME; kt += 64) {
    const int t = kt >> 10;
    const int k = kt & 1023;
    const int kA = (t == 2 ? 1024 : 0) + k;
    const int kB = (t == 1 ? 1024 : 0) + k;

#pragma unroll
    for (int is = 0; is < 4; is++) {
      const int s  = is * 256 + tid;
      const int r  = s >> 3;
      const int kq = s & 7;
      const int csw = kq ^ (r & 7);
      const int ldsOff = __builtin_amdgcn_readfirstlane((is * 256 + wave * 64) * 16);
      void* gA = (void*)(Acat + (size_t)(arow + r) * 2048 + kA + csw * 8);
      lds_dma16(gA, (char*)sA + ldsOff);
      int n = bcol + r; if (n >= NTRAIN) n = NTRAIN - 1;
      void* gB = (void*)(Bcat + (size_t)n * 2048 + kB + csw * 8);
      lds_dma16(gB, (char*)sB + ldsOff);
    }
    asm volatile("s_waitcnt vmcnt(0)" ::: "memory");
    __syncthreads();

#pragma unroll
    for (int ks = 0; ks < 2; ks++) {
      bf16x8 aF[4], bF[4];
      const int c = ks * 4 + quad;
#pragma unroll
      for (int i = 0; i < 4; i++) {
        const int m = wm * 64 + i * 16 + m16;
        aF[i] = *(const bf16x8*)(sA + (size_t)(m * 8 + (c ^ (m & 7))) * 8);
        const int n = wn * 64 + i * 16 + m16;
        bF[i] = *(const bf16x8*)(sB + (size_t)(n * 8 + (c ^ (n & 7))) * 8);
      }
#pragma unroll
      for (int i = 0; i < 4; i++)
#pragma unroll
        for (int j = 0; j < 4; j++)
          acc[i][j] = __builtin_amdgcn_mfma_f32_16x16x32_bf16(aF[i], bF[j], acc[i][j], 0, 0, 0);
    }
    __syncthreads();
  }

#pragma unroll
  for (int i = 0; i < 4; i++) {
    const int mr = rowL + wm * 64 + i * 16 + quad * 4;
#pragma unroll
    for (int j = 0; j < 4; j++) {
      const int col = bcol + wn * 64 + j * 16 + m16;
      if (col < NTRAIN) {
#pragma unroll
        for (int r = 0; r < 4; r++)
          C[(size_t)(mr + r) * NTRAIN + col] = acc[i][j][r];
      }
    }
  }
}

// ---------------------------------------------------- top-k + softmax -------
// One block per row. Single global read (plus 8KB sample):
//  S) sample 1024 values, bitonic sort -> t0 = 26th largest (q~0.975), t1.
//  1) stream row once: v>=t0 -> stash (key|~idx) in LDS + linear hist.
//  2) suffix-sum hist -> b* (largest bin with count(>=bin) >= 200).
//  3) filter stash by bin>=b* -> cand2 -> sort -> softmax -> 4 snapshots.
//  Fallbacks: retry with widened range; global re-read compact on overflow.
__global__ __launch_bounds__(256)
void topk_hist(const float* __restrict__ sim, const int* __restrict__ labels,
               float* __restrict__ out, int row0) {
  __shared__ unsigned long long stash[STCAP];   // 38.0 KB
  __shared__ unsigned long long cand2[C2CAP];   // 8 KB (aliases as hist)
  __shared__ float ch[NCLS];                    // 4 KB
  __shared__ unsigned int csum[256];
  __shared__ unsigned int s_cnt, s_sel, s_bstar;
  __shared__ float s_wsum, s_lo, s_hi;

  unsigned int* hist = (unsigned int*)cand2;    // HB u32 == C2CAP u64
  const int tid = threadIdx.x;
  const float* srow = sim + (size_t)blockIdx.x * NTRAIN;
  const int grow = row0 + blockIdx.x;

  auto bsort = [&](unsigned long long* buf, int P) {
    for (int k2 = 2; k2 <= P; k2 <<= 1)
      for (int j = k2 >> 1; j > 0; j >>= 1) {
        for (int m = tid; m < P; m += 256) {
          int l = m ^ j;
          if (l > m) {
            unsigned long long x = buf[m], y = buf[l];
            bool desc = ((m & k2) == 0);
            if (desc ? (x < y) : (x > y)) { buf[m] = y; buf[l] = x; }
          }
        }
        __syncthreads();
      }
  };

  // ---- S: sample ----
  float* smp = (float*)stash;
  {
    int base = (tid >> 4) * 6250 + (tid & 15) * 4;   // 16 coalesced chunks
    float4 v = *(const float4*)(srow + base);
    *(float4*)(smp + tid * 4) = v;
  }
  __syncthreads();
  for (int k2 = 2; k2 <= 1024; k2 <<= 1)
    for (int j = k2 >> 1; j > 0; j >>= 1) {
      for (int m = tid; m < 1024; m += 256) {
        int l = m ^ j;
        if (l > m) {
          float x = smp[m], y = smp[l];
          bool desc = ((m & k2) == 0);
          if (desc ? (x < y) : (x > y)) { smp[m] = y; smp[l] = x; }
        }
      }
      __syncthreads();
    }
  if (tid == 0) {
    float t0 = smp[25], tmax = smp[0];
    float t1 = tmax + 1.5f * (tmax - t0);
    s_lo = t0; s_hi = t1;
  }
  __syncthreads();

  // ---- 1+2: stream + threshold (with retry) ----
  for (int att = 0; att < 3; att++) {
    for (int i = tid; i < HB; i += 256) hist[i] = 0;
    if (tid == 0) { s_cnt = 0; s_sel = 0; }
    __syncthreads();
    const float lo = s_lo;
    const float scale = 2046.0f / fmaxf(s_hi - lo, 1e-30f);
    const float nls = -lo * scale;

    auto proc = [&](float v, int idx) {
      if (v >= lo) {
        unsigned p = atomicAdd(&s_cnt, 1u);
        float f = __builtin_fmaf(v, scale, nls);
        int bin = 1 + (int)fminf(fmaxf(f, 0.f), 2046.f);
        atomicAdd(&hist[bin], 1u);
        if (p < STCAP) {
          unsigned u = __float_as_uint(v);
          unsigned key = u ^ ((unsigned)((int)u >> 31) | 0x80000000u);
          stash[p] = ((unsigned long long)key << 32) | (unsigned)(~idx);
        }
      }
    };

#pragma unroll 4
    for (int it = 0; it < 97; it++) {
      int i = it * 1024 + tid * 4;
      float4 v4 = *(const float4*)(srow + i);
      proc(v4.x, i); proc(v4.y, i + 1); proc(v4.z, i + 2); proc(v4.w, i + 3);
    }
    // tail: FULL strided coverage of 99328..99999 (round-3 bug was here)
    for (int i = 97 * 1024 + tid; i < NTRAIN; i += 256) proc(srow[i], i);
    __syncthreads();

    unsigned s = 0;
    const int base = tid * (HB / 256);
#pragma unroll
    for (int b = 0; b < HB / 256; b++) s += hist[base + b];
    csum[tid] = s;
    __syncthreads();
    unsigned suf = 0;
    for (int j = tid + 1; j < 256; j++) suf += csum[j];
    if (suf < MAXK && suf + s >= MAXK) {
      unsigned run = suf;
      for (int b = HB / 256 - 1; b >= 0; b--) {
        unsigned h = hist[base + b];
        if (run + h >= MAXK) { s_bstar = (unsigned)(base + b); break; }
        run += h;
      }
    }
    __syncthreads();
    if (s_cnt >= MAXK) break;                 // threshold valid
    if (tid == 0) s_lo = s_lo - 8.0f * (s_hi - s_lo);   // widen & retry
    __syncthreads();
  }

  const unsigned bstar = s_bstar;
  const float lo = s_lo;
  const float scale = 2046.0f / fmaxf(s_hi - lo, 1e-30f);
  const float nls = -lo * scale;
  const unsigned cnt = s_cnt;

  // ---- 3: candidates ----
  unsigned long long* buf;
  int cnt2;
  bool fast = (cnt <= STCAP);
  if (fast) {
    for (unsigned i = tid; i < cnt; i += 256) {
      unsigned long long e = stash[i];
      unsigned key = (unsigned)(e >> 32);
      unsigned u = key ^ ((unsigned)((int)(~key) >> 31) | 0x80000000u);
      float v = __uint_as_float(u);
      float f = __builtin_fmaf(v, scale, nls);
      int bin = 1 + (int)fminf(fmaxf(f, 0.f), 2046.f);
      if ((unsigned)bin >= bstar) {
        unsigned p = atomicAdd(&s_sel, 1u);
        if (p < C2CAP) cand2[p] = e;
      }
    }
    __syncthreads();
    if (s_sel > C2CAP) fast = false;
  }
  if (fast) {
    buf = cand2; cnt2 = (int)s_sel;
  } else {
    if (tid == 0) s_sel = 0;
    __syncthreads();
    for (int i = tid; i < NTRAIN; i += 256) {
      float v = srow[i];
      if (v >= lo) {
        float f = __builtin_fmaf(v, scale, nls);
        int bin = 1 + (int)fminf(fmaxf(f, 0.f), 2046.f);
        if ((unsigned)bin >= bstar) {
          unsigned p = atomicAdd(&s_sel, 1u);
          if (p < SLOWCAP) {
            unsigned u = __float_as_uint(v);
            unsigned key = u ^ ((unsigned)((int)u >> 31) | 0x80000000u);
            stash[p] = ((unsigned long long)key << 32) | (unsigned)(~i);
          }
        }
      }
    }
    __syncthreads();
    buf = stash;
    cnt2 = (int)s_sel; if (cnt2 > SLOWCAP) cnt2 = SLOWCAP;
  }

  int P = 256; while (P < cnt2) P <<= 1;
  for (int i = cnt2 + tid; i < P; i += 256) buf[i] = 0ull;
  __syncthreads();
  bsort(buf, P);

  // ---- softmax + snapshots ----
  if (tid == 0) s_wsum = 0.f;
  for (int i = tid; i < NCLS; i += 256) ch[i] = 0.f;
  __syncthreads();

  unsigned kp0 = (unsigned)(buf[0] >> 32);
  unsigned u0 = kp0 ^ ((unsigned)((int)(~kp0) >> 31) | 0x80000000u);
  float v0 = __uint_as_float(u0);

  float wi = 0.f; int lab = 0;
  if (tid < MAXK) {
    unsigned long long e = buf[tid];
    unsigned kp = (unsigned)(e >> 32);
    unsigned u = kp ^ ((unsigned)((int)(~kp) >> 31) | 0x80000000u);
    float v = __uint_as_float(u);
    int idx = (int)(~(unsigned)(e & 0xFFFFFFFFull));
    lab = labels[idx];
    wi = expf((v - v0) * INV_T);
    atomicAdd(&s_wsum, wi);
  }
  __syncthreads();
  float wn = (tid < MAXK) ? (wi / s_wsum) : 0.f;

  const int kb[5] = {0, 10, 20, 100, 200};
#pragma unroll
  for (int ph = 0; ph < 4; ph++) {
    if (tid >= kb[ph] && tid < kb[ph + 1]) atomicAdd(&ch[lab], wn);
    __syncthreads();
    float* dst = out + ((size_t)ph * B_Q + grow) * NCLS;
    for (int i = tid; i < NCLS; i += 256) dst[i] = ch[i];
    __syncthreads();
  }
}

// ---------------------------------------------------------------- launch ----
extern "C" void kernel_launch(void* const* d_in, const int* in_sizes, int n_in,
                              void* d_out, int out_size, void* d_ws, size_t ws_size,
                              hipStream_t stream) {
  const float* A      = (const float*)d_in[0];
  const float* B      = (const float*)d_in[1];
  const int*   labels = (const int*)d_in[2];
  float* out = (float*)d_out;

  char* ws = (char*)d_ws;
  const size_t acat_bytes = (size_t)B_Q * 2048 * 2;
  const size_t bcat_bytes = (size_t)NTRAIN * 2048 * 2;
  __bf16* Acat = (__bf16*)ws;
  __bf16* Bcat = (__bf16*)(ws + acat_bytes);
  float*  sim  = (float*)(ws + acat_bytes + bcat_bytes);

  size_t sim_bytes = (ws_size > acat_bytes + bcat_bytes)
                       ? ws_size - acat_bytes - bcat_bytes : 0;
  long rows_fit = (long)(sim_bytes / ((size_t)NTRAIN * sizeof(float)));
  int chunk = (int)((rows_fit / 128) * 128);
  if (chunk > B_Q) chunk = B_Q;
  if (chunk < 128) chunk = 128;

  split_hi_lo<<<dim3(256),  dim3(256), 0, stream>>>(A, Acat, B_Q);
  split_hi_lo<<<dim3(2048), dim3(256), 0, stream>>>(B, Bcat, NTRAIN);

  for (int row0 = 0; row0 < B_Q; row0 += chunk) {
    int nr = (B_Q - row0 < chunk) ? (B_Q - row0) : chunk;
    dim3 gg(nr / 128, (NTRAIN + 127) / 128);
    gemm_mfma<<<gg, dim3(256), 0, stream>>>(Acat, Bcat, sim, row0);
    topk_hist<<<dim3(nr), dim3(256), 0, stream>>>(sim, labels, out, row0);
  }
}

// Round 5
// 2130.185 us; speedup vs baseline: 2.6560x; 1.0535x over previous
//
#include <hip/hip_runtime.h>
#include <hip/hip_bf16.h>
#include <stdint.h>

// KNN classifier pipeline (round 5: sim matrix never materialized):
//   split-bf16 MFMA GEMM (K'=3072) with FUSED filter epilogue:
//     sample GEMM (2048 cols) -> per-row threshold -> main GEMM keeps only
//     values >= thr[row] in a compact per-row candidate buffer (~732/row)
//   finish: sort candidates -> softmax(T=0.07) -> 4 class-histogram snapshots.
//
// Round-4 post-mortem: ~1050us of non-GEMM time, dominated by topk_hist's
// 819MB sim read (+800MB sim write inside gemm). Both eliminated here.

#define B_Q     2048
#define DIM     1024
#define NTRAIN  100000
#define MAXK    200
#define NCLS    1000
#define INV_T   (1.0f/0.07f)
#define KPRIME  3072
#define NSAMP   2048      // sample columns for thresholding
#define SSTRIDE 48        // sample train index = n*48+17  (max 98273 < 100000)
#define SOFF    17
#define R0      15        // thr = 15th largest sample -> E[count]~732, sd~27
#define CAPR    4096      // per-row candidate capacity (120 sigma headroom)

typedef __bf16 bf16x8 __attribute__((ext_vector_type(8)));
typedef float  f32x4  __attribute__((ext_vector_type(4)));

// --------------------------------------------------------------- utils ------
__global__ __launch_bounds__(256)
void zero_u32(unsigned int* __restrict__ p, int n) {
  int i = blockIdx.x * 256 + threadIdx.x;
  if (i < n) p[i] = 0u;
}

// --------------------------------------------------------------- split ------
// grid-stride, 8 floats/iter: deep MLP. Y row: [hi x1024 | lo x1024].
__global__ __launch_bounds__(256)
void split_hi_lo(const float* __restrict__ X, __bf16* __restrict__ Y, int rows) {
  const int nth = gridDim.x * 256;
  const int total = rows * (DIM / 8);
  for (int g = blockIdx.x * 256 + threadIdx.x; g < total; g += nth) {
    const int row = g >> 7, c8 = (g & 127) * 8;
    const float* p = X + (size_t)row * DIM + c8;
    float4 a = ((const float4*)p)[0], b = ((const float4*)p)[1];
    float f[8] = {a.x, a.y, a.z, a.w, b.x, b.y, b.z, b.w};
    bf16x8 h, l;
#pragma unroll
    for (int j = 0; j < 8; j++) {
      __bf16 hi = (__bf16)f[j];
      h[j] = hi;
      l[j] = (__bf16)(f[j] - (float)hi);
    }
    *(bf16x8*)(Y + (size_t)row * 2048 + c8) = h;
    *(bf16x8*)(Y + (size_t)row * 2048 + 1024 + c8) = l;
  }
}

// ---------------------------------------------------------------- GEMM ------
__device__ __forceinline__ void lds_dma16(void* g, void* l) {
  __builtin_amdgcn_global_load_lds((__attribute__((address_space(1))) void*)g,
                                   (__attribute__((address_space(3))) void*)l,
                                   16, 0, 0);
}

// Sample GEMM: 2048 x 2048 over strided train rows, writes ssim fp32.
// Same tile/K' structure as main GEMM -> bitwise-identical values.
__global__ __launch_bounds__(256, 2)
void gemm_sample(const __bf16* __restrict__ Acat, const __bf16* __restrict__ Bcat,
                 float* __restrict__ ssim) {
  __shared__ __bf16 sA[128 * 64];
  __shared__ __bf16 sB[128 * 64];

  const int tid  = threadIdx.x;
  const int lane = tid & 63;
  const int wave = tid >> 6;
  const int wm = wave & 1, wn = wave >> 1;
  const int m16 = lane & 15, quad = lane >> 4;
  const int arow = blockIdx.x * 128;
  const int bcol = blockIdx.y * 128;

  f32x4 acc[4][4];
#pragma unroll
  for (int i = 0; i < 4; i++)
#pragma unroll
    for (int j = 0; j < 4; j++) acc[i][j] = (f32x4){0.f, 0.f, 0.f, 0.f};

  for (int kt = 0; kt < KPRIME; kt += 64) {
    const int t = kt >> 10;
    const int k = kt & 1023;
    const int kA = (t == 2 ? 1024 : 0) + k;
    const int kB = (t == 1 ? 1024 : 0) + k;

#pragma unroll
    for (int is = 0; is < 4; is++) {
      const int s  = is * 256 + tid;
      const int r  = s >> 3;
      const int kq = s & 7;
      const int csw = kq ^ (r & 7);
      const int ldsOff = __builtin_amdgcn_readfirstlane((is * 256 + wave * 64) * 16);
      void* gA = (void*)(Acat + (size_t)(arow + r) * 2048 + kA + csw * 8);
      lds_dma16(gA, (char*)sA + ldsOff);
      int n = (bcol + r) * SSTRIDE + SOFF;
      void* gB = (void*)(Bcat + (size_t)n * 2048 + kB + csw * 8);
      lds_dma16(gB, (char*)sB + ldsOff);
    }
    asm volatile("s_waitcnt vmcnt(0)" ::: "memory");
    __syncthreads();

#pragma unroll
    for (int ks = 0; ks < 2; ks++) {
      bf16x8 aF[4], bF[4];
      const int c = ks * 4 + quad;
#pragma unroll
      for (int i = 0; i < 4; i++) {
        const int m = wm * 64 + i * 16 + m16;
        aF[i] = *(const bf16x8*)(sA + (size_t)(m * 8 + (c ^ (m & 7))) * 8);
        const int n = wn * 64 + i * 16 + m16;
        bF[i] = *(const bf16x8*)(sB + (size_t)(n * 8 + (c ^ (n & 7))) * 8);
      }
#pragma unroll
      for (int i = 0; i < 4; i++)
#pragma unroll
        for (int j = 0; j < 4; j++)
          acc[i][j] = __builtin_amdgcn_mfma_f32_16x16x32_bf16(aF[i], bF[j], acc[i][j], 0, 0, 0);
    }
    __syncthreads();
  }

#pragma unroll
  for (int i = 0; i < 4; i++) {
    const int mr = arow + wm * 64 + i * 16 + quad * 4;
#pragma unroll
    for (int j = 0; j < 4; j++) {
      const int col = bcol + wn * 64 + j * 16 + m16;
#pragma unroll
      for (int r = 0; r < 4; r++)
        ssim[(size_t)(mr + r) * NSAMP + col] = acc[i][j][r];
    }
  }
}

// Per-row threshold: sort 2048 sample sims desc, thr = R0-th largest.
__global__ __launch_bounds__(256)
void row_threshold(const float* __restrict__ ssim, float* __restrict__ thr) {
  __shared__ float smp[NSAMP];
  const int tid = threadIdx.x;
  const float* srow = ssim + (size_t)blockIdx.x * NSAMP;
  for (int i = tid; i < NSAMP; i += 256) smp[i] = srow[i];
  __syncthreads();
  for (int k2 = 2; k2 <= NSAMP; k2 <<= 1)
    for (int j = k2 >> 1; j > 0; j >>= 1) {
      for (int m = tid; m < NSAMP; m += 256) {
        int l = m ^ j;
        if (l > m) {
          float x = smp[m], y = smp[l];
          bool desc = ((m & k2) == 0);
          if (desc ? (x < y) : (x > y)) { smp[m] = y; smp[l] = x; }
        }
      }
      __syncthreads();
    }
  if (tid == 0) thr[blockIdx.x] = smp[R0 - 1];
}

// Main GEMM with fused filter epilogue: no C matrix; values >= thr[row] go
// to a compact per-row candidate list via device atomics.
__global__ __launch_bounds__(256, 2)
void gemm_filter(const __bf16* __restrict__ Acat, const __bf16* __restrict__ Bcat,
                 const float* __restrict__ thr, unsigned int* __restrict__ gcnt,
                 unsigned long long* __restrict__ cand) {
  __shared__ __bf16 sA[128 * 64];
  __shared__ __bf16 sB[128 * 64];
  __shared__ float sT[128];

  const int tid  = threadIdx.x;
  const int lane = tid & 63;
  const int wave = tid >> 6;
  const int wm = wave & 1, wn = wave >> 1;
  const int m16 = lane & 15, quad = lane >> 4;
  const int arow = blockIdx.x * 128;
  const int bcol = blockIdx.y * 128;

  if (tid < 128) sT[tid] = thr[arow + tid];   // barriers in K-loop cover this

  f32x4 acc[4][4];
#pragma unroll
  for (int i = 0; i < 4; i++)
#pragma unroll
    for (int j = 0; j < 4; j++) acc[i][j] = (f32x4){0.f, 0.f, 0.f, 0.f};

  for (int kt = 0; kt < KPRIME; kt += 64) {
    const int t = kt >> 10;
    const int k = kt & 1023;
    const int kA = (t == 2 ? 1024 : 0) + k;
    const int kB = (t == 1 ? 1024 : 0) + k;

#pragma unroll
    for (int is = 0; is < 4; is++) {
      const int s  = is * 256 + tid;
      const int r  = s >> 3;
      const int kq = s & 7;
      const int csw = kq ^ (r & 7);
      const int ldsOff = __builtin_amdgcn_readfirstlane((is * 256 + wave * 64) * 16);
      void* gA = (void*)(Acat + (size_t)(arow + r) * 2048 + kA + csw * 8);
      lds_dma16(gA, (char*)sA + ldsOff);
      int n = bcol + r; if (n >= NTRAIN) n = NTRAIN - 1;
      void* gB = (void*)(Bcat + (size_t)n * 2048 + kB + csw * 8);
      lds_dma16(gB, (char*)sB + ldsOff);
    }
    asm volatile("s_waitcnt vmcnt(0)" ::: "memory");
    __syncthreads();

#pragma unroll
    for (int ks = 0; ks < 2; ks++) {
      bf16x8 aF[4], bF[4];
      const int c = ks * 4 + quad;
#pragma unroll
      for (int i = 0; i < 4; i++) {
        const int m = wm * 64 + i * 16 + m16;
        aF[i] = *(const bf16x8*)(sA + (size_t)(m * 8 + (c ^ (m & 7))) * 8);
        const int n = wn * 64 + i * 16 + m16;
        bF[i] = *(const bf16x8*)(sB + (size_t)(n * 8 + (c ^ (n & 7))) * 8);
      }
#pragma unroll
      for (int i = 0; i < 4; i++)
#pragma unroll
        for (int j = 0; j < 4; j++)
          acc[i][j] = __builtin_amdgcn_mfma_f32_16x16x32_bf16(aF[i], bF[j], acc[i][j], 0, 0, 0);
    }
    __syncthreads();
  }

  // filter epilogue
#pragma unroll
  for (int i = 0; i < 4; i++) {
    const int lrB = wm * 64 + i * 16 + quad * 4;
#pragma unroll
    for (int j = 0; j < 4; j++) {
      const int col = bcol + wn * 64 + j * 16 + m16;
      if (col < NTRAIN) {
#pragma unroll
        for (int r = 0; r < 4; r++) {
          float v = acc[i][j][r];
          int lr = lrB + r;
          if (v >= sT[lr]) {
            unsigned p = atomicAdd(&gcnt[arow + lr], 1u);
            if (p < CAPR) {
              unsigned u = __float_as_uint(v);
              unsigned key = u ^ ((unsigned)((int)u >> 31) | 0x80000000u);
              cand[(size_t)(arow + lr) * CAPR + p] =
                  ((unsigned long long)key << 32) | (unsigned)(~col);
            }
          }
        }
      }
    }
  }
}

// ------------------------------------------------------------- finish -------
// One block per row: sort candidates desc -> softmax top-200 -> 4 snapshots.
__global__ __launch_bounds__(256)
void finish(const unsigned long long* __restrict__ cand,
            const unsigned int* __restrict__ gcnt,
            const int* __restrict__ labels, float* __restrict__ out) {
  __shared__ unsigned long long stash[CAPR];   // 32 KB
  __shared__ float ch[NCLS];                   // 4 KB
  __shared__ float s_wsum;

  const int tid = threadIdx.x;
  const int row = blockIdx.x;
  unsigned cc = gcnt[row];
  int c = (cc > CAPR) ? CAPR : (int)cc;
  const unsigned long long* crow = cand + (size_t)row * CAPR;

  for (int i = tid; i < c; i += 256) stash[i] = crow[i];
  int P = 256; while (P < c) P <<= 1;
  for (int i = c + tid; i < P; i += 256) stash[i] = 0ull;
  if (tid == 0) s_wsum = 0.f;
  for (int i = tid; i < NCLS; i += 256) ch[i] = 0.f;
  __syncthreads();

  for (int k2 = 2; k2 <= P; k2 <<= 1)
    for (int j = k2 >> 1; j > 0; j >>= 1) {
      for (int m = tid; m < P; m += 256) {
        int l = m ^ j;
        if (l > m) {
          unsigned long long x = stash[m], y = stash[l];
          bool desc = ((m & k2) == 0);
          if (desc ? (x < y) : (x > y)) { stash[m] = y; stash[l] = x; }
        }
      }
      __syncthreads();
    }

  unsigned kp0 = (unsigned)(stash[0] >> 32);
  unsigned u0 = kp0 ^ ((unsigned)((int)(~kp0) >> 31) | 0x80000000u);
  float v0 = __uint_as_float(u0);

  float wi = 0.f; int lab = 0;
  if (tid < MAXK) {
    unsigned long long e = stash[tid];
    unsigned kp = (unsigned)(e >> 32);
    unsigned u = kp ^ ((unsigned)((int)(~kp) >> 31) | 0x80000000u);
    float v = __uint_as_float(u);
    int idx = (int)(~(unsigned)(e & 0xFFFFFFFFull));
    lab = labels[idx];
    wi = expf((v - v0) * INV_T);
    atomicAdd(&s_wsum, wi);
  }
  __syncthreads();
  float wn = (tid < MAXK) ? (wi / s_wsum) : 0.f;

  const int kb[5] = {0, 10, 20, 100, 200};
#pragma unroll
  for (int ph = 0; ph < 4; ph++) {
    if (tid >= kb[ph] && tid < kb[ph + 1]) atomicAdd(&ch[lab], wn);
    __syncthreads();
    float* dst = out + ((size_t)ph * B_Q + row) * NCLS;
    for (int i = tid; i < NCLS; i += 256) dst[i] = ch[i];
    __syncthreads();
  }
}

// ---------------------------------------------------------------- launch ----
extern "C" void kernel_launch(void* const* d_in, const int* in_sizes, int n_in,
                              void* d_out, int out_size, void* d_ws, size_t ws_size,
                              hipStream_t stream) {
  const float* A      = (const float*)d_in[0];
  const float* B      = (const float*)d_in[1];
  const int*   labels = (const int*)d_in[2];
  float* out = (float*)d_out;

  char* ws = (char*)d_ws;
  size_t off = 0;
  __bf16* Acat = (__bf16*)(ws + off); off += (size_t)B_Q * 2048 * 2;       // 8.4 MB
  __bf16* Bcat = (__bf16*)(ws + off); off += (size_t)NTRAIN * 2048 * 2;    // 409.6 MB
  float*  ssim = (float*)(ws + off);  off += (size_t)B_Q * NSAMP * 4;      // 16.8 MB
  float*  thr  = (float*)(ws + off);  off += (size_t)B_Q * 4;
  unsigned int* gcnt = (unsigned int*)(ws + off); off += (size_t)B_Q * 4;
  unsigned long long* cand = (unsigned long long*)(ws + off);              // 67.1 MB
  // total ~502 MB; ws proven >= 1.23 GB in rounds 2/4.

  zero_u32<<<dim3(8), dim3(256), 0, stream>>>(gcnt, B_Q);
  split_hi_lo<<<dim3(256),  dim3(256), 0, stream>>>(A, Acat, B_Q);
  split_hi_lo<<<dim3(2048), dim3(256), 0, stream>>>(B, Bcat, NTRAIN);

  gemm_sample<<<dim3(B_Q / 128, NSAMP / 128), dim3(256), 0, stream>>>(Acat, Bcat, ssim);
  row_threshold<<<dim3(B_Q), dim3(256), 0, stream>>>(ssim, thr);

  gemm_filter<<<dim3(B_Q / 128, (NTRAIN + 127) / 128), dim3(256), 0, stream>>>(
      Acat, Bcat, thr, gcnt, cand);
  finish<<<dim3(B_Q), dim3(256), 0, stream>>>(cand, gcnt, labels, out);
}